// Round 7
// baseline (115.315 us; speedup 1.0000x reference)
//
#include <hip/hip_runtime.h>

// CapsNet routing: N=32, C=32, D=16(=P*P), S=256, K=10, n_rout=3.
// 4 graph nodes: 3x iter_mfma + final. No atomics, no memset, no spins.
// Phases 3/4 on MFMA 16x16x32 bf16 (phase3 split hi/lo both operands ->
// ~fp32 b for softmax; phase4 ct bf16 x lr split hi/lo).
// iter mode 0: vec = g;  mode 1: vec = squash(sum_c sp_in)  (guarded sn>0).

#define KK 10
#define PP 16
#define CC 32
#define SS 256
#define NN 32

typedef __attribute__((ext_vector_type(8))) short short8;
typedef __attribute__((ext_vector_type(4))) float f32x4;
typedef __attribute__((ext_vector_type(4))) unsigned int uint4v;
typedef __attribute__((ext_vector_type(2))) unsigned int uint2v;

__device__ inline unsigned short f2bf(float f) {   // RNE float->bf16
  unsigned u = __float_as_uint(f);
  u += 0x7FFFu + ((u >> 16) & 1u);
  return (unsigned short)(u >> 16);
}
__device__ inline float bf2f(unsigned short h) {
  return __uint_as_float(((unsigned)h) << 16);
}

__global__ __launch_bounds__(256, 2) void iter_mfma(
    const float* __restrict__ l,       // [N][C][16][256]
    const float* __restrict__ w,       // [C][K][4][4]
    const float* __restrict__ g,       // [N][K][16]   (mode 0)
    const float* __restrict__ sp_in,   // [N][C][160]  (mode 1)
    float* __restrict__ sp_out,        // [N][C][160]
    const int mode)
{
  const int bid  = blockIdx.x;
  const int n    = bid >> 5;
  const int c    = bid & 31;
  const int t    = threadIdx.x;
  const int wv   = t >> 6;           // wave 0-3
  const int lrow = t & 15;
  const int quad = (t >> 4) & 3;

  __shared__ unsigned short lrA_hi[SS * 16];    // [s][ij]  (phase3 A)
  __shared__ unsigned short lrA_lo[SS * 16];
  __shared__ unsigned short lrB_hi[16 * 264];   // [ij][s]  (phase4 B)
  __shared__ unsigned short lrB_lo[16 * 264];
  __shared__ unsigned short ct[16 * 264];       // [k][s]   (phase4 A)
  __shared__ unsigned short U_hi[16 * 24];      // [k][ij]  (phase3 B)
  __shared__ unsigned short U_lo[16 * 24];
  __shared__ float M_lds[PP * PP];
  __shared__ float w_lds[KK * PP];
  __shared__ float gc_lds[KK * PP];
  __shared__ float f_lds[KK];

  // ---------- staging ----------
  if (t < KK * PP) w_lds[t] = w[c * KK * PP + t];
  if (t >= 160 && t < 256) {           // zero U rows 10..15 (phase3 B pad)
    const int r6 = t - 160;
    const int kr = 10 + (r6 >> 4), ij = r6 & 15;
    U_hi[kr * 24 + ij] = 0;
    U_lo[kr * 24 + ij] = 0;
  }
  {
    float lr[PP];
    unsigned short hi[PP], lo[PP];
    const float* lb = l + (size_t)(n * CC + c) * (PP * SS) + t;
    #pragma unroll
    for (int d = 0; d < PP; ++d) {
      lr[d] = lb[d * SS];              // coalesced
      hi[d] = f2bf(lr[d]);
      lo[d] = f2bf(lr[d] - bf2f(hi[d]));
    }
    uint4v ph0 = { (unsigned)hi[0] | ((unsigned)hi[1] << 16),
                   (unsigned)hi[2] | ((unsigned)hi[3] << 16),
                   (unsigned)hi[4] | ((unsigned)hi[5] << 16),
                   (unsigned)hi[6] | ((unsigned)hi[7] << 16) };
    uint4v ph1 = { (unsigned)hi[8]  | ((unsigned)hi[9]  << 16),
                   (unsigned)hi[10] | ((unsigned)hi[11] << 16),
                   (unsigned)hi[12] | ((unsigned)hi[13] << 16),
                   (unsigned)hi[14] | ((unsigned)hi[15] << 16) };
    uint4v pl0 = { (unsigned)lo[0] | ((unsigned)lo[1] << 16),
                   (unsigned)lo[2] | ((unsigned)lo[3] << 16),
                   (unsigned)lo[4] | ((unsigned)lo[5] << 16),
                   (unsigned)lo[6] | ((unsigned)lo[7] << 16) };
    uint4v pl1 = { (unsigned)lo[8]  | ((unsigned)lo[9]  << 16),
                   (unsigned)lo[10] | ((unsigned)lo[11] << 16),
                   (unsigned)lo[12] | ((unsigned)lo[13] << 16),
                   (unsigned)lo[14] | ((unsigned)lo[15] << 16) };
    *(uint4v*)&lrA_hi[t * 16]     = ph0;
    *(uint4v*)&lrA_hi[t * 16 + 8] = ph1;
    *(uint4v*)&lrA_lo[t * 16]     = pl0;
    *(uint4v*)&lrA_lo[t * 16 + 8] = pl1;
    #pragma unroll
    for (int d = 0; d < PP; ++d) {      // [ij][s] transpose: pair via shfl
      const int ph = __shfl_xor((int)(unsigned)hi[d], 1);
      const int pl = __shfl_xor((int)(unsigned)lo[d], 1);
      if (!(t & 1)) {
        *(unsigned*)&lrB_hi[d * 264 + t] = (unsigned)hi[d] | (((unsigned)ph) << 16);
        *(unsigned*)&lrB_lo[d * 264 + t] = (unsigned)lo[d] | (((unsigned)pl) << 16);
      }
    }
  }

  // ---------- vec = g or squash(sum_c sp_in) ----------
  if (mode == 0) {
    if (t < KK * PP) gc_lds[t] = g[n * KK * PP + t];
    __syncthreads();
  } else {
    if (t < KK * PP) {
      float sv = 0.f;
      #pragma unroll 8
      for (int c2 = 0; c2 < CC; ++c2)
        sv += sp_in[(n * CC + c2) * (KK * PP) + t];
      gc_lds[t] = sv;
    }
    __syncthreads();
    if (t < KK) {
      float sn = 0.f;
      #pragma unroll
      for (int m = 0; m < PP; ++m) { const float v = gc_lds[t * PP + m]; sn += v * v; }
      f_lds[t] = (sn > 0.f) ? sn / (1.f + sn) * rsqrtf(sn) : 0.f;
    }
    __syncthreads();
    if (t < KK * PP) gc_lds[t] *= f_lds[t >> 4];
    __syncthreads();
  }

  // ---------- U[k][i*4+j] = sum_dd w[c,k,j,dd]*gc[k,i*4+dd] -> bf16 hi/lo ----
  if (t < KK * PP) {
    const int k = t >> 4, ij = t & 15, i = ij >> 2, j = ij & 3;
    const float* wp = w_lds + k * PP + j * 4;
    const float* vp = gc_lds + k * PP + i * 4;
    const float u = wp[0]*vp[0] + wp[1]*vp[1] + wp[2]*vp[2] + wp[3]*vp[3];
    const unsigned short uh = f2bf(u);
    U_hi[k * 24 + ij] = uh;
    U_lo[k * 24 + ij] = f2bf(u - bf2f(uh));
  }

  // phase-3 A-fragments (doesn't touch U; overlap with U writes)
  const short8 zs = {0,0,0,0,0,0,0,0};
  short8 Ahi[4], Alo[4];
  {
    const int col8 = (quad & 1) * 8;
    #pragma unroll
    for (int tt = 0; tt < 4; ++tt) {
      const int srow = (wv * 4 + tt) * 16 + lrow;
      Ahi[tt] = (quad < 2) ? *(const short8*)&lrA_hi[srow * 16 + col8] : zs;
      Alo[tt] = (quad < 2) ? *(const short8*)&lrA_lo[srow * 16 + col8] : zs;
    }
  }
  __syncthreads();

  // ---------- phase 3: b = lr . U^T (split: AloBhi + AhiBlo + AhiBhi) ----------
  {
    const int col8 = (quad & 1) * 8;
    const short8 Bhi = (quad < 2) ? *(const short8*)&U_hi[lrow * 24 + col8] : zs;
    const short8 Blo = (quad < 2) ? *(const short8*)&U_lo[lrow * 24 + col8] : zs;
    const bool kv = (lrow < KK);
    #pragma unroll
    for (int tt = 0; tt < 4; ++tt) {
      f32x4 a = {0.f, 0.f, 0.f, 0.f};
      a = __builtin_amdgcn_mfma_f32_16x16x32_bf16(Alo[tt], Bhi, a, 0, 0, 0);
      a = __builtin_amdgcn_mfma_f32_16x16x32_bf16(Ahi[tt], Blo, a, 0, 0, 0);
      a = __builtin_amdgcn_mfma_f32_16x16x32_bf16(Ahi[tt], Bhi, a, 0, 0, 0);
      // softmax over k (= lanes 0..15 of the 16-group), rows s=quad*4+rg
      float cc[4];
      #pragma unroll
      for (int rg = 0; rg < 4; ++rg) {
        const float bv = a[rg];
        float mx = kv ? bv : -1e30f;
        mx = fmaxf(mx, __shfl_xor(mx, 1));
        mx = fmaxf(mx, __shfl_xor(mx, 2));
        mx = fmaxf(mx, __shfl_xor(mx, 4));
        mx = fmaxf(mx, __shfl_xor(mx, 8));
        float e = kv ? __expf(bv - mx) : 0.f;
        float sm = e;
        sm += __shfl_xor(sm, 1);
        sm += __shfl_xor(sm, 2);
        sm += __shfl_xor(sm, 4);
        sm += __shfl_xor(sm, 8);
        cc[rg] = e / sm;
      }
      const int scol = (wv * 4 + tt) * 16 + quad * 4;   // ct[k=lrow][s=scol..+3]
      uint2v pk = { (unsigned)f2bf(cc[0]) | (((unsigned)f2bf(cc[1])) << 16),
                    (unsigned)f2bf(cc[2]) | (((unsigned)f2bf(cc[3])) << 16) };
      *(uint2v*)&ct[lrow * 264 + scol] = pk;
    }
  }
  __syncthreads();

  // ---------- phase 4: M[k][ij] = sum_s ct[k][s]*lr[s][ij] ----------
  {
    f32x4 mh = {0.f, 0.f, 0.f, 0.f};
    f32x4 ml = {0.f, 0.f, 0.f, 0.f};
    #pragma unroll
    for (int Kt = 0; Kt < 8; ++Kt) {
      const int off = Kt * 32 + quad * 8;
      const short8 af = *(const short8*)&ct[lrow * 264 + off];
      mh = __builtin_amdgcn_mfma_f32_16x16x32_bf16(
               af, *(const short8*)&lrB_hi[lrow * 264 + off], mh, 0, 0, 0);
      ml = __builtin_amdgcn_mfma_f32_16x16x32_bf16(
               af, *(const short8*)&lrB_lo[lrow * 264 + off], ml, 0, 0, 0);
    }
    if (t < 64) {                       // wave 0 result (all waves redundant)
      #pragma unroll
      for (int rg = 0; rg < 4; ++rg)
        M_lds[(quad * 4 + rg) * PP + lrow] = mh[rg] + ml[rg];
    }
  }
  __syncthreads();

  // ---------- phase 6: sp[k][i*4+d] = sum_j M[k][i*4+j]*w[c,k,j,d] ----------
  if (t < KK * PP) {
    const int k = t >> 4, i = (t >> 2) & 3, d = t & 3;
    const float* Mp = M_lds + k * PP + i * 4;
    const float* wp = w_lds + k * PP + d;
    sp_out[(n * CC + c) * (KK * PP) + t] =
        Mp[0]*wp[0] + Mp[1]*wp[4] + Mp[2]*wp[8] + Mp[3]*wp[12];
  }
}

__global__ __launch_bounds__(256) void final_kernel(
    const float* __restrict__ sp_in,   // [N][C][160]
    float* __restrict__ out_a,         // [N][K]
    float* __restrict__ out_gc)        // [N][K][16]
{
  const int n = blockIdx.x;
  const int t = threadIdx.x;
  __shared__ float s_lds[KK * PP];
  __shared__ float f_lds[KK];
  if (t < KK * PP) {
    float sv = 0.f;
    #pragma unroll 8
    for (int c2 = 0; c2 < CC; ++c2)
      sv += sp_in[(n * CC + c2) * (KK * PP) + t];
    s_lds[t] = sv;
  }
  __syncthreads();
  if (t < KK) {
    float sn = 0.f;
    #pragma unroll
    for (int m = 0; m < PP; ++m) { const float v = s_lds[t * PP + m]; sn += v * v; }
    f_lds[t] = (sn > 0.f) ? sn / (1.f + sn) * rsqrtf(sn) : 0.f;
    const float gn = sn / (1.f + sn);   // = |gc|
    out_a[n * KK + t] = 1.f / (1.f + __expf(-gn));
  }
  __syncthreads();
  if (t < KK * PP) out_gc[n * KK * PP + t] = s_lds[t] * f_lds[t >> 4];
}

extern "C" void kernel_launch(void* const* d_in, const int* in_sizes, int n_in,
                              void* d_out, int out_size, void* d_ws, size_t ws_size,
                              hipStream_t stream) {
  (void)in_sizes; (void)n_in; (void)out_size; (void)ws_size;
  const float* l = (const float*)d_in[0];
  const float* g = (const float*)d_in[1];
  const float* w = (const float*)d_in[2];

  float* out    = (float*)d_out;
  float* out_a  = out;
  float* out_gc = out + NN * KK;

  float* sp_a = (float*)d_ws;                  // [N][C][160]
  float* sp_b = sp_a + NN * CC * KK * PP;
  float* sp_c = sp_b + NN * CC * KK * PP;

  iter_mfma<<<NN * CC, 256, 0, stream>>>(l, w, g, nullptr, sp_a, 0);
  iter_mfma<<<NN * CC, 256, 0, stream>>>(l, w, nullptr, sp_a, sp_b, 1);
  iter_mfma<<<NN * CC, 256, 0, stream>>>(l, w, nullptr, sp_b, sp_c, 1);
  final_kernel<<<NN, 256, 0, stream>>>(sp_c, out_a, out_gc);
}

// Round 8
// 93.459 us; speedup vs baseline: 1.2339x; 1.2339x over previous
//
#include <hip/hip_runtime.h>

// CapsNet routing: N=32, C=32, D=16(=P*P), S=W*H=256, K=10, n_rout=3.
// 4 graph nodes: 3x iter_kernel + final_kernel. No memset (sp fully
// overwritten each iter), no atomics, no fences, no spins.
// R4's proven fp32 phases; sp is c-minor [n][160][32] so the in-kernel
// c-reduce is 8 contiguous dwordx4 per thread.

#define KK 10
#define PP 16
#define CC 32
#define SS 256
#define NN 32

__global__ __launch_bounds__(256, 4) void iter_kernel(
    const float* __restrict__ l,       // [N][C][16][256]
    const float* __restrict__ w,       // [C][K][4][4]
    const float* __restrict__ g,       // [N][K][16]      (mode 0)
    const float* __restrict__ sp_in,   // [N][160][32]    (mode 1)
    float* __restrict__ sp_out,        // [N][160][32]
    const int mode)
{
  const int bid = blockIdx.x;
  const int n = bid >> 5;
  const int c = bid & 31;
  const int t = threadIdx.x;           // t == s in phases 3-4

  __shared__ float lr_lds[PP][SS + 4];     // [ij][s]
  __shared__ float ct[KK][SS + 4];         // softmax weights [k][s]
  __shared__ float U_lds[KK * PP];         // U; reused for M
  __shared__ float w_lds[KK * PP];         // w[c]
  __shared__ float gc_lds[KK * PP];        // g or squash(sum_c sp_in)
  __shared__ float f_lds[KK];
  __shared__ float part[KK][PP][PP + 1];   // chunk partials of M

  // ---- stage w[c] and this block's l slice ----
  if (t < KK * PP) w_lds[t] = w[c * KK * PP + t];
  float lr[PP];
  const float* lb = l + (size_t)(n * CC + c) * (PP * SS) + t;
  #pragma unroll
  for (int d = 0; d < PP; ++d) {
    lr[d] = lb[d * SS];                 // coalesced across t
    lr_lds[d][t] = lr[d];
  }

  // ---- vec = g (mode 0) or squash(sum_c sp_in) (mode 1) ----
  if (mode == 0) {
    if (t < KK * PP) gc_lds[t] = g[n * KK * PP + t];
    __syncthreads();
  } else {
    if (t < KK * PP) {
      const float4* p = (const float4*)(sp_in + ((size_t)n * KK * PP + t) * CC);
      float4 a = p[0];
      #pragma unroll
      for (int q = 1; q < 8; ++q) {
        const float4 v = p[q];
        a.x += v.x; a.y += v.y; a.z += v.z; a.w += v.w;
      }
      gc_lds[t] = a.x + a.y + a.z + a.w;
    }
    __syncthreads();
    if (t < KK) {
      float sn = 0.f;
      #pragma unroll
      for (int m = 0; m < PP; ++m) { const float v = gc_lds[t * PP + m]; sn += v * v; }
      f_lds[t] = (sn > 0.f) ? sn / (1.f + sn) * rsqrtf(sn) : 0.f;
    }
    __syncthreads();
    if (t < KK * PP) gc_lds[t] *= f_lds[t >> 4];
    __syncthreads();
  }

  // ---- U[k][i*4+j] = sum_dd w[c,k,j,dd] * gc[k,i*4+dd] ----
  if (t < KK * PP) {
    const int k = t >> 4, ij = t & 15, i = ij >> 2, j = ij & 3;
    const float4 wv = *(const float4*)&w_lds[k * PP + j * 4];
    const float4 gv = *(const float4*)&gc_lds[k * PP + i * 4];
    U_lds[t] = wv.x * gv.x + wv.y * gv.y + wv.z * gv.z + wv.w * gv.w;
  }
  __syncthreads();

  // ---- b[k] = lr . U[k]; softmax over k; store ct[k][s] ----
  {
    float b[KK];
    float bmax = -1e30f;
    #pragma unroll
    for (int k = 0; k < KK; ++k) {
      float acc = 0.f;
      #pragma unroll
      for (int d4 = 0; d4 < 4; ++d4) {
        const float4 uv = *(const float4*)&U_lds[k * PP + d4 * 4];  // wave-uniform broadcast
        acc += lr[d4*4+0]*uv.x + lr[d4*4+1]*uv.y + lr[d4*4+2]*uv.z + lr[d4*4+3]*uv.w;
      }
      b[k] = acc;
      bmax = fmaxf(bmax, acc);
    }
    float ssum = 0.f;
    #pragma unroll
    for (int k = 0; k < KK; ++k) { b[k] = __expf(b[k] - bmax); ssum += b[k]; }
    const float inv = 1.f / ssum;
    #pragma unroll
    for (int k = 0; k < KK; ++k) ct[k][t] = b[k] * inv;
  }
  __syncthreads();

  // ---- M[k][ij] = sum_s ct[k][s]*lr[ij][s]: 256 thr, 16-s chunks ----
  {
    const int ch = t >> 4;        // 16 chunks of 16 s
    const int ij = t & 15;
    const int sbase = ch * 16;
    float acc[KK];
    #pragma unroll
    for (int k = 0; k < KK; ++k) acc[k] = 0.f;
    #pragma unroll
    for (int s4 = 0; s4 < 4; ++s4) {
      const float4 lv = *(const float4*)&lr_lds[ij][sbase + s4 * 4];
      #pragma unroll
      for (int k = 0; k < KK; ++k) {
        const float4 cv = *(const float4*)&ct[k][sbase + s4 * 4];
        acc[k] += cv.x*lv.x + cv.y*lv.y + cv.z*lv.z + cv.w*lv.w;
      }
    }
    #pragma unroll
    for (int k = 0; k < KK; ++k) part[k][ij][ch] = acc[k];
  }
  __syncthreads();

  // ---- merge chunk partials -> M (into U_lds) ----
  if (t < KK * PP) {
    const int k = t >> 4, ij = t & 15;
    float m = 0.f;
    #pragma unroll
    for (int s4 = 0; s4 < 4; ++s4) {
      const float4 pv = *(const float4*)&part[k][ij][s4 * 4];
      m += pv.x + pv.y + pv.z + pv.w;
    }
    U_lds[t] = m;   // U dead; now holds M
  }
  __syncthreads();

  // ---- sp[k][i*4+d] = sum_j M[k][i*4+j]*w[c,k,j,d]  (c-minor store) ----
  if (t < KK * PP) {
    const int k = t >> 4, i = (t >> 2) & 3, d = t & 3;
    const float* Mp = U_lds + k * PP + i * 4;
    const float* wp = w_lds + k * PP + d;
    sp_out[((size_t)n * KK * PP + t) * CC + c] =
        Mp[0]*wp[0] + Mp[1]*wp[4] + Mp[2]*wp[8] + Mp[3]*wp[12];
  }
}

__global__ __launch_bounds__(256) void final_kernel(
    const float* __restrict__ sp_in,   // [N][160][32]
    float* __restrict__ out_a,         // [N][K]
    float* __restrict__ out_gc)        // [N][K][16]
{
  const int n = blockIdx.x;
  const int t = threadIdx.x;
  __shared__ float s_lds[KK * PP];
  __shared__ float f_lds[KK];
  if (t < KK * PP) {
    const float4* p = (const float4*)(sp_in + ((size_t)n * KK * PP + t) * CC);
    float4 a = p[0];
    #pragma unroll
    for (int q = 1; q < 8; ++q) {
      const float4 v = p[q];
      a.x += v.x; a.y += v.y; a.z += v.z; a.w += v.w;
    }
    s_lds[t] = a.x + a.y + a.z + a.w;
  }
  __syncthreads();
  if (t < KK) {
    float sn = 0.f;
    #pragma unroll
    for (int m = 0; m < PP; ++m) { const float v = s_lds[t * PP + m]; sn += v * v; }
    f_lds[t] = (sn > 0.f) ? sn / (1.f + sn) * rsqrtf(sn) : 0.f;
    const float gn = sn / (1.f + sn);   // = |gc|
    out_a[n * KK + t] = 1.f / (1.f + __expf(-gn));
  }
  __syncthreads();
  if (t < KK * PP) out_gc[n * KK * PP + t] = s_lds[t] * f_lds[t >> 4];
}

extern "C" void kernel_launch(void* const* d_in, const int* in_sizes, int n_in,
                              void* d_out, int out_size, void* d_ws, size_t ws_size,
                              hipStream_t stream) {
  (void)in_sizes; (void)n_in; (void)out_size; (void)ws_size;
  const float* l = (const float*)d_in[0];
  const float* g = (const float*)d_in[1];
  const float* w = (const float*)d_in[2];

  float* out    = (float*)d_out;
  float* out_a  = out;
  float* out_gc = out + NN * KK;

  float* sp_a = (float*)d_ws;                  // [N][160][32]
  float* sp_b = sp_a + NN * KK * PP * CC;
  float* sp_c = sp_b + NN * KK * PP * CC;

  iter_kernel<<<NN * CC, 256, 0, stream>>>(l, w, g, nullptr, sp_a, 0);
  iter_kernel<<<NN * CC, 256, 0, stream>>>(l, w, nullptr, sp_a, sp_b, 1);
  iter_kernel<<<NN * CC, 256, 0, stream>>>(l, w, nullptr, sp_b, sp_c, 1);
  final_kernel<<<NN, 256, 0, stream>>>(sp_c, out_a, out_gc);
}